// Round 5
// baseline (252.379 us; speedup 1.0000x reference)
//
#include <hip/hip_runtime.h>

typedef __bf16 bf16;
typedef _Float16 f16;
typedef __bf16 bf16x8 __attribute__((ext_vector_type(8)));
typedef _Float16 f16x4 __attribute__((ext_vector_type(4)));
typedef _Float16 f16x8 __attribute__((ext_vector_type(8)));
typedef float f32x4 __attribute__((ext_vector_type(4)));
typedef float f32x16 __attribute__((ext_vector_type(16)));

// async global->LDS, 16B/lane. LDS dest = wave-uniform base + lane*16.
__device__ __forceinline__ void async16(const void* g, void* l) {
  __builtin_amdgcn_global_load_lds(
      (const __attribute__((address_space(1))) unsigned int*)g,
      (__attribute__((address_space(3))) unsigned int*)l, 16, 0, 0);
}

// pack two f32 -> one dword of 2x bf16 (no builtin on gfx950)
__device__ __forceinline__ unsigned cvtpk(float a, float b) {
  unsigned r;
  asm("v_cvt_pk_bf16_f32 %0, %1, %2" : "=v"(r) : "v"(a), "v"(b));
  return r;
}

// exchange a[32..63] <-> b[0..31]
__device__ __forceinline__ void swap32(unsigned& a, unsigned& b) {
  asm("v_permlane32_swap_b32 %0, %1" : "+v"(a), "+v"(b));
}

// ---------------------------------------------------------------------------
// Cast fp32 -> fp16, vectorized x4
// ---------------------------------------------------------------------------
__global__ __launch_bounds__(256) void castx(const float* __restrict__ in,
                                             f16* __restrict__ out) {
  long i = ((long)blockIdx.x * 256 + threadIdx.x) * 4;
  f32x4 v = *(const f32x4*)(in + i);
  f16x4 o;
#pragma unroll
  for (int j = 0; j < 4; j++) o[j] = (f16)v[j];
  *(f16x4*)(out + i) = o;
}

// ---------------------------------------------------------------------------
// Transpose + cast: float in[R][C] -> f16 out[C][R].  block (32,8)
// ---------------------------------------------------------------------------
__global__ __launch_bounds__(256) void tcast(const float* __restrict__ in,
                                             f16* __restrict__ out, int R, int C) {
  __shared__ float tile[32][33];
  int tx = threadIdx.x, ty = threadIdx.y;
  int c = blockIdx.x * 32 + tx;
#pragma unroll
  for (int i = 0; i < 4; i++) {
    int r = blockIdx.y * 32 + ty + i * 8;
    tile[ty + i * 8][tx] = in[(long)r * C + c];
  }
  __syncthreads();
  int c2 = blockIdx.y * 32 + tx;
#pragma unroll
  for (int i = 0; i < 4; i++) {
    int r2 = blockIdx.x * 32 + ty + i * 8;
    out[(long)r2 * R + c2] = (f16)tile[tx][ty + i * 8];
  }
}

// ---------------------------------------------------------------------------
// V transpose: f16 src (qkv_f + 2048, row stride 3072) -> bf16 vtf in
// MFMA-fragment order: vtf element index for (bh, d, n):
//   (((bh*32 + n>>6)*8 + (d>>5)*4 + ((n&63)>>4))*64 + ((n>>3)&1)*32 + (d&31))*8 + (n&7)
// i.e. per (bh, kb) 8 units of 1KB; unit u = dt*4 + uks; lane l = hi*32+l31
// holds V^T[dt*32 + l31][kb*64 + uks*16 + hi*8 .. +8].
// ---------------------------------------------------------------------------
__global__ __launch_bounds__(256) void vtrans(const f16* __restrict__ src,
                                              bf16* __restrict__ vtf) {
  __shared__ f16 tile[32][33];
  int tx = threadIdx.x, ty = threadIdx.y;
  int n0 = blockIdx.x * 32, d0 = blockIdx.y * 32, bh = blockIdx.z;
  int b = bh >> 4, h = bh & 15;
#pragma unroll
  for (int i = 0; i < 4; i++) {
    int n = n0 + ty + i * 8;
    tile[ty + i * 8][tx] = src[(long)(b * 2048 + n) * 3072 + h * 64 + d0 + tx];
  }
  __syncthreads();
#pragma unroll
  for (int i = 0; i < 4; i++) {
    int d = d0 + ty + i * 8;
    int n = n0 + tx;
    long off = ((((long)bh * 32 + (n >> 6)) * 8 + (d >> 5) * 4 + ((n & 63) >> 4)) * 64 +
                ((n >> 3) & 1) * 32 + (d & 31)) * 8 + (n & 7);
    vtf[off] = (bf16)(float)tile[tx][ty + i * 8];
  }
}

// ---------------------------------------------------------------------------
// fp16 1-term GEMM: C[M,N] = A[M,K] @ B[N,K]^T. 128x128 tile, BK=32,
// fragment-order async staging, double-buffered (1 barrier/iter).
// 512 threads / 8 waves: wave = (wm 0..3, wn 0..1), 32x64 output each,
// acc[2][4]. Staging 2 async16/wave (A-tile w, B-tile w).
// MODE 0: fp32 partials via blockIdx.z split-K. MODE 1: f16 out.
// ---------------------------------------------------------------------------
template <int MODE>
__global__ __launch_bounds__(512) void gemm_f16(const f16* __restrict__ A_g,
                                                const f16* __restrict__ B_g,
                                                float* __restrict__ p0,
                                                float* __restrict__ p1,
                                                f16* __restrict__ outh,
                                                int M, int N, int K) {
  __shared__ __align__(16) f16 AL[2][4096], BL[2][4096];
  int t = threadIdx.x, lane = t & 63, w = t >> 6;
  int wm = w >> 1, wn = w & 1;
  int m0 = blockIdx.y * 128, n0 = blockIdx.x * 128;
  int fm = lane & 15, fq = lane >> 4;
  int kseg = K / gridDim.z;
  int kstart = blockIdx.z * kseg;
  int nk = kseg / 32;

  const f16* ap = A_g + (long)(m0 + w * 16 + fm) * K + kstart + fq * 8;
  const f16* bp = B_g + (long)(n0 + w * 16 + fm) * K + kstart + fq * 8;

  f32x4 acc[2][4];
#pragma unroll
  for (int i = 0; i < 2; i++)
#pragma unroll
    for (int j = 0; j < 4; j++) acc[i][j] = f32x4{0.f, 0.f, 0.f, 0.f};

  // prefetch tile 0 into buffer 0
  async16(ap, &AL[0][w * 512]);
  async16(bp, &BL[0][w * 512]);

  for (int it = 0; it < nk; it++) {
    int cur = it & 1;
    __syncthreads();  // drains prefetch for tile `it`; waves done with cur^1
    if (it < nk - 1) {
      int ko = (it + 1) * 32;
      async16(ap + ko, &AL[cur ^ 1][w * 512]);
      async16(bp + ko, &BL[cur ^ 1][w * 512]);
    }
    f16x8 a[2], bfr[4];
#pragma unroll
    for (int i = 0; i < 2; i++)
      a[i] = *(const f16x8*)&AL[cur][(wm * 2 + i) * 512 + lane * 8];
#pragma unroll
    for (int j = 0; j < 4; j++)
      bfr[j] = *(const f16x8*)&BL[cur][(wn * 4 + j) * 512 + lane * 8];
#pragma unroll
    for (int i = 0; i < 2; i++)
#pragma unroll
      for (int j = 0; j < 4; j++)
        acc[i][j] = __builtin_amdgcn_mfma_f32_16x16x32_f16(a[i], bfr[j], acc[i][j], 0, 0, 0);
  }

  float* dst = blockIdx.z ? p1 : p0;
#pragma unroll
  for (int i = 0; i < 2; i++)
#pragma unroll
    for (int j = 0; j < 4; j++) {
      int c = n0 + (wn * 4 + j) * 16 + fm;
#pragma unroll
      for (int e = 0; e < 4; e++) {
        int r = m0 + (wm * 2 + i) * 16 + fq * 4 + e;
        if (MODE == 0)
          dst[(long)r * N + c] = acc[i][j][e];
        else
          outh[(long)r * N + c] = (f16)acc[i][j][e];
      }
    }
}

// ---------------------------------------------------------------------------
// out = p0 + p1 + bias   (fp32, 4096x1024)
// ---------------------------------------------------------------------------
__global__ __launch_bounds__(256) void addbias(const float* __restrict__ p0,
                                               const float* __restrict__ p1,
                                               const float* __restrict__ bias,
                                               float* __restrict__ out) {
  long i = ((long)blockIdx.x * 256 + threadIdx.x) * 4;
  f32x4 a = *(const f32x4*)(p0 + i);
  f32x4 b = *(const f32x4*)(p1 + i);
  f32x4 c = *(const f32x4*)(bias + (i & 1023));
  *(f32x4*)(out + i) = a + b + c;
}

// ---------------------------------------------------------------------------
// RMSNorm (inner=1024) + RoPE, fp16 in (qkv_f, stride 3072), fp16 out.
// grid (4096, 2): y==0 -> q row-major (scale 1/8); y==1 -> k in MFMA-fragment
// order: element (b, h, key n, col dl=ks*16+hi*8+jj) at
//   ((((b*16+h)*32 + n>>6)*8 + ((n>>5)&1)*4 + ks)*64 + hi*32 + (n&31))*8 + jj
// ---------------------------------------------------------------------------
__global__ __launch_bounds__(256) void normrope(const f16* __restrict__ src,
                                                const float* __restrict__ wqn,
                                                const float* __restrict__ wkn,
                                                f16* __restrict__ qf,
                                                f16* __restrict__ kff) {
  int row = blockIdx.x, which = blockIdx.y;
  const f16* sp = src + (long)row * 3072 + which * 1024;
  const float* w = which ? wkn : wqn;
  float scale = which ? 1.0f : 0.125f;
  int t = threadIdx.x;
  int j0 = t * 4;

  f16x4 xh = *(const f16x4*)(sp + j0);
  float xv[4];
#pragma unroll
  for (int j = 0; j < 4; j++) xv[j] = (float)xh[j];
  float ss = xv[0] * xv[0] + xv[1] * xv[1] + xv[2] * xv[2] + xv[3] * xv[3];
#pragma unroll
  for (int off = 32; off > 0; off >>= 1) ss += __shfl_down(ss, off);
  __shared__ float red[4];
  if ((t & 63) == 0) red[t >> 6] = ss;
  __syncthreads();
  float total = red[0] + red[1] + red[2] + red[3];
  float nsc = rsqrtf(total * (1.0f / 1024.0f) + 1e-6f) * scale;

  int n = row & 2047;
  f16x4 o;
#pragma unroll
  for (int pp = 0; pp < 2; pp++) {
    int j = j0 + 2 * pp;
    int ii = (j & 63) >> 1;
    float theta = __expf((float)ii * (-9.210340371976184f / 32.0f));
    float ang = (float)n * theta;
    float sn, cs;
    __sincosf(ang, &sn, &cs);
    float a0 = xv[2 * pp] * nsc * w[j];
    float a1 = xv[2 * pp + 1] * nsc * w[j + 1];
    o[2 * pp] = (f16)(cs * a0 - sn * a1);
    o[2 * pp + 1] = (f16)(sn * a0 + cs * a1);
  }
  if (which == 0) {
    *(f16x4*)(qf + (long)row * 1024 + j0) = o;
  } else {
    int b2 = row >> 11;
    int h2 = j0 >> 6, dl = j0 & 63;
    long off = ((((long)(b2 * 16 + h2) * 32 + (n >> 6)) * 8 + ((n >> 5) & 1) * 4 +
                 (dl >> 4)) * 64 + ((dl >> 3) & 1) * 32 + (n & 31)) * 8 + (dl & 7);
    *(f16x4*)(kff + off) = o;
  }
}

// ---------------------------------------------------------------------------
// MFMA flash attention v6 = v5's verified structure (4 waves/256 thr, k-split
// z = b*2+ksp, swapped-operand S^T=mfma(K,Q), in-register P pack, pO/pl +
// combine) with FRAGMENT-LINEAR LDS: K/V arrive pre-fragmented from
// normrope/vtrans, staging is contiguous (src + lane*16 -> linear LDS), and
// all ds_read_b128 are lane-linear (unit*1024 + lane*16) = the HW-verified
// conflict-free pattern (v1 counters: +0.44 cyc/read vs v5 swizzle +4).
// K unit u = nt*4+ks: lane l holds K[kb*64+nt*32+(l&31)][h*64+ks*16+(l>>5)*8..]
// V unit u = dt*4+ks: lane l holds V^T[dt*32+(l&31)][kb*64+ks*16+(l>>5)*8..]
// ---------------------------------------------------------------------------
__global__ __launch_bounds__(256) void attn_mfma(const f16* __restrict__ qf,
                                                 const f16* __restrict__ kff,
                                                 const bf16* __restrict__ vtf,
                                                 f16* __restrict__ pO,
                                                 float* __restrict__ pl) {
  __shared__ __align__(16) f16 KhL[2][4096];   // 8 units x 1KB per buf
  __shared__ __align__(16) bf16 VtL[2][4096];  // 8 units x 1KB per buf

  int t = threadIdx.x;
  int lane = t & 63, w = t >> 6;  // wave w owns q-rows q0 + w*32 .. +32
  int lo5 = lane & 31, hi = lane >> 5;
  int z = blockIdx.z;
  int b = z >> 1, ksp = z & 1;
  int h = blockIdx.y, q0 = blockIdx.x * 128;

  // Q B-frags (whole kernel): lane -> Q[q0+w*32+lo5][h*64 + ks*16 + hi*8 + j]
  const f16* qb = qf + ((long)(b * 2048 + q0 + w * 32 + lo5)) * 1024 + h * 64 + hi * 8;
  f16x8 qfr[4];
#pragma unroll
  for (int ks = 0; ks < 4; ks++) qfr[ks] = *(const f16x8*)(qb + ks * 16);

  // staging: per tile kb, 8 K units + 8 V units of 1KB; wave w stages units
  // 2w, 2w+1 (contiguous source: fragment buffer + lane*16).
  const f16* kg = kff + ((long)(b * 16 + h)) * 131072 + (2 * w) * 512 + lane * 8;
  const bf16* vg = vtf + ((long)(b * 16 + h)) * 131072 + (2 * w) * 512 + lane * 8;

  f32x16 Ot[2];
#pragma unroll
  for (int i = 0; i < 16; i++) {
    Ot[0][i] = 0.f;
    Ot[1][i] = 0.f;
  }
  float l_ = 0.f;

  int kb0 = ksp * 16;  // this block's half of the 32 k-tiles

#define STAGE(buf, kb)                                                     \
  {                                                                        \
    async16(kg + (long)(kb) * 4096, (char*)KhL[buf] + (2 * w) * 1024);     \
    async16(kg + (long)(kb) * 4096 + 512,                                  \
            (char*)KhL[buf] + (2 * w + 1) * 1024);                         \
    async16(vg + (long)(kb) * 4096, (char*)VtL[buf] + (2 * w) * 1024);     \
    async16(vg + (long)(kb) * 4096 + 512,                                  \
            (char*)VtL[buf] + (2 * w + 1) * 1024);                         \
  }

  STAGE(0, kb0);

  for (int it = 0; it < 16; it++) {
    int cur = it & 1;
    __syncthreads();  // drains tile-it prefetch; all waves off buffer cur^1
    if (it < 15) STAGE(cur ^ 1, kb0 + it + 1);

    const char* kbase = (const char*)KhL[cur];
    const char* vbase = (const char*)VtL[cur];

    // S^T = K Q^T : two 32(k)x32(q) tiles; lane-linear reads
    f32x16 s0, s1;
#pragma unroll
    for (int i = 0; i < 16; i++) {
      s0[i] = 0.f;
      s1[i] = 0.f;
    }
#pragma unroll
    for (int ks = 0; ks < 4; ks++) {
      f16x8 k0 = *(const f16x8*)(kbase + ks * 1024 + (long)lane * 16);
      f16x8 k1 = *(const f16x8*)(kbase + (4 + ks) * 1024 + (long)lane * 16);
      s0 = __builtin_amdgcn_mfma_f32_32x32x16_f16(k0, qfr[ks], s0, 0, 0, 0);
      s1 = __builtin_amdgcn_mfma_f32_32x32x16_f16(k1, qfr[ks], s1, 0, 0, 0);
    }

    // p = exp(s); per-lane l sum (q = lo5 fixed); pack PV B-frags in-register.
    union PF {
      unsigned u[4];
      bf16x8 v;
    } pf[4];
#pragma unroll
    for (int nt = 0; nt < 2; nt++) {
      f32x16 s = nt ? s1 : s0;
      float pv[16];
#pragma unroll
      for (int r = 0; r < 16; r++) {
        pv[r] = __expf(s[r]);
        l_ += pv[r];
      }
#pragma unroll
      for (int g = 0; g < 2; g++) {
        unsigned c01 = cvtpk(pv[g * 8 + 0], pv[g * 8 + 1]);
        unsigned c23 = cvtpk(pv[g * 8 + 2], pv[g * 8 + 3]);
        unsigned c45 = cvtpk(pv[g * 8 + 4], pv[g * 8 + 5]);
        unsigned c67 = cvtpk(pv[g * 8 + 6], pv[g * 8 + 7]);
        swap32(c01, c45);  // -> frag dwords 0 and 2
        swap32(c23, c67);  // -> frag dwords 1 and 3
        pf[nt * 2 + g].u[0] = c01;
        pf[nt * 2 + g].u[1] = c23;
        pf[nt * 2 + g].u[2] = c45;
        pf[nt * 2 + g].u[3] = c67;
      }
    }

    // O^T += V^T P^T : two 32(d)x32(q) tiles; lane-linear reads
#pragma unroll
    for (int ks = 0; ks < 4; ks++) {
      bf16x8 v0 = *(const bf16x8*)(vbase + ks * 1024 + (long)lane * 16);
      bf16x8 v1 = *(const bf16x8*)(vbase + (4 + ks) * 1024 + (long)lane * 16);
      Ot[0] = __builtin_amdgcn_mfma_f32_32x32x16_bf16(v0, pf[ks].v, Ot[0], 0, 0, 0);
      Ot[1] = __builtin_amdgcn_mfma_f32_32x32x16_bf16(v1, pf[ks].v, Ot[1], 0, 0, 0);
    }
  }
#undef STAGE

  // lane + its hi-partner hold complementary k halves for q=lo5
  l_ += __shfl_xor(l_, 32);
  float inv = 1.0f / l_;

  // per-split store: pO[ksp][b][h][q][d], d = dt*32 + (r&3)+8*(r>>2)+4*hi
  long rowi = ((long)((ksp * 2 + b) * 16 + h)) * 2048 + q0 + w * 32 + lo5;
  f16* op = pO + rowi * 64;
#pragma unroll
  for (int dt = 0; dt < 2; dt++)
#pragma unroll
    for (int g4 = 0; g4 < 4; g4++) {
      f16x4 o4;
#pragma unroll
      for (int e = 0; e < 4; e++) o4[e] = (f16)(Ot[dt][g4 * 4 + e] * inv);
      *(f16x4*)(op + dt * 32 + g4 * 8 + hi * 4) = o4;
    }
  if (hi == 0) pl[rowi] = l_;
}

// ---------------------------------------------------------------------------
// combine the two k-split halves: af = (O0*l0 + O1*l1)/(l0+l1), f16 out.
// block 256 thr = 16 q-rows x 16 d-groups(x4); grid (128, 16, 2).
// ---------------------------------------------------------------------------
__global__ __launch_bounds__(256) void attn_combine(const f16* __restrict__ pO,
                                                    const float* __restrict__ pl,
                                                    f16* __restrict__ af) {
  int dg = threadIdx.x & 15;
  int qi = threadIdx.x >> 4;
  int q = blockIdx.x * 16 + qi;
  int h = blockIdx.y, b = blockIdx.z;
  long r0 = ((long)(b * 16 + h)) * 2048 + q;
  long r1 = ((long)((2 + b) * 16 + h)) * 2048 + q;
  float l0 = pl[r0], l1 = pl[r1];
  float w0 = l0 / (l0 + l1), w1 = 1.0f - w0;
  f16x4 a = *(const f16x4*)(pO + r0 * 64 + dg * 4);
  f16x4 c = *(const f16x4*)(pO + r1 * 64 + dg * 4);
  f16x4 o;
#pragma unroll
  for (int e = 0; e < 4; e++) o[e] = (f16)((float)a[e] * w0 + (float)c[e] * w1);
  *(f16x4*)(af + ((long)(b * 2048 + q)) * 1024 + h * 64 + dg * 4) = o;
}

// ---------------------------------------------------------------------------
// Workspace (MB, peak 62; 76 proven safe), liveness:
//   [ 0, 8): xf        castx -> qkv-GEMM
//   [ 8,14): Wqkv_t    tcast x2 -> qkv-GEMM
//   [14,38): qkv_f     GEMM -> normrope / vtrans
//   [38,46): qf        normrope -> attn
//   [46,54): kff       normrope (fragment order) -> attn
//   [54,62): vtf       vtrans (fragment order) -> attn
//   [14,30): pO        attn partials -> combine   (qkv_f dead)
//   [30,31): pl        attn denominators -> combine
//   [ 0, 8): af        combine -> out-GEMM        (xf dead)
//   [ 8,10): Wo_t      tcast -> out-GEMM          (Wqkv_t dead)
//   [14,30): p0        out-GEMM -> addbias        (pO dead)
//   [30,46): p1        out-GEMM -> addbias        (pl + qf dead)
// ---------------------------------------------------------------------------
extern "C" void kernel_launch(void* const* d_in, const int* in_sizes, int n_in,
                              void* d_out, int out_size, void* d_ws, size_t ws_size,
                              hipStream_t stream) {
  const float* x = (const float*)d_in[0];
  const float* Wq = (const float*)d_in[1];
  const float* Wkv = (const float*)d_in[2];
  const float* nqw = (const float*)d_in[3];
  const float* nkw = (const float*)d_in[4];
  const float* Wo = (const float*)d_in[5];
  const float* bo = (const float*)d_in[6];
  float* out = (float*)d_out;

  char* ws = (char*)d_ws;
  const long MB = 1l << 20;
  f16* xf     = (f16*)(ws);
  f16* Wqkv_t = (f16*)(ws + 8 * MB);
  f16* qkv_f  = (f16*)(ws + 14 * MB);
  f16* qfb    = (f16*)(ws + 38 * MB);
  f16* kffb   = (f16*)(ws + 46 * MB);
  bf16* vtfb  = (bf16*)(ws + 54 * MB);
  f16* pOb    = (f16*)(ws + 14 * MB);
  float* plb  = (float*)(ws + 30 * MB);
  f16* afb    = (f16*)(ws);
  f16* Wo_t   = (f16*)(ws + 8 * MB);
  float* p0   = (float*)(ws + 14 * MB);
  float* p1   = (float*)(ws + 30 * MB);

  dim3 tb(32, 8);
  castx<<<4096, 256, 0, stream>>>(x, xf);
  tcast<<<dim3(32, 32), tb, 0, stream>>>(Wq, Wqkv_t, 1024, 1024);
  tcast<<<dim3(64, 32), tb, 0, stream>>>(Wkv, Wqkv_t + 1024l * 1024, 1024, 2048);

  gemm_f16<1><<<dim3(24, 32), 512, 0, stream>>>(xf, Wqkv_t, nullptr, nullptr,
                                                qkv_f, 4096, 3072, 1024);

  normrope<<<dim3(4096, 2), 256, 0, stream>>>(qkv_f, nqw, nkw, qfb, kffb);

  vtrans<<<dim3(64, 2, 32), tb, 0, stream>>>(qkv_f + 2048, vtfb);

  attn_mfma<<<dim3(16, 16, 4), 256, 0, stream>>>(qfb, kffb, vtfb, pOb, plb);

  attn_combine<<<dim3(128, 16, 2), 256, 0, stream>>>(pOb, plb, afb);

  tcast<<<dim3(32, 32), tb, 0, stream>>>(Wo, Wo_t, 1024, 1024);

  gemm_f16<0><<<dim3(8, 32, 2), 512, 0, stream>>>(afb, Wo_t, p0, p1, nullptr,
                                                  4096, 1024, 1024);

  addbias<<<4096, 256, 0, stream>>>(p0, p1, bo, out);
}

// Round 6
// 252.062 us; speedup vs baseline: 1.0013x; 1.0013x over previous
//
#include <hip/hip_runtime.h>

typedef __bf16 bf16;
typedef _Float16 f16;
typedef __bf16 bf16x8 __attribute__((ext_vector_type(8)));
typedef _Float16 f16x4 __attribute__((ext_vector_type(4)));
typedef _Float16 f16x8 __attribute__((ext_vector_type(8)));
typedef float f32x4 __attribute__((ext_vector_type(4)));
typedef float f32x16 __attribute__((ext_vector_type(16)));

// async global->LDS, 16B/lane. LDS dest = wave-uniform base + lane*16.
__device__ __forceinline__ void async16(const void* g, void* l) {
  __builtin_amdgcn_global_load_lds(
      (const __attribute__((address_space(1))) unsigned int*)g,
      (__attribute__((address_space(3))) unsigned int*)l, 16, 0, 0);
}

// pack two f32 -> one dword of 2x bf16 (no builtin on gfx950)
__device__ __forceinline__ unsigned cvtpk(float a, float b) {
  unsigned r;
  asm("v_cvt_pk_bf16_f32 %0, %1, %2" : "=v"(r) : "v"(a), "v"(b));
  return r;
}

// exchange a[32..63] <-> b[0..31]
__device__ __forceinline__ void swap32(unsigned& a, unsigned& b) {
  asm("v_permlane32_swap_b32 %0, %1" : "+v"(a), "+v"(b));
}

// raw v_exp_f32: 2^x (q is pre-scaled by log2e upstream)
__device__ __forceinline__ float exp2i(float x) {
  float r;
  asm("v_exp_f32 %0, %1" : "=v"(r) : "v"(x));
  return r;
}

// ---------------------------------------------------------------------------
// Cast fp32 -> fp16, vectorized x4
// ---------------------------------------------------------------------------
__global__ __launch_bounds__(256) void castx(const float* __restrict__ in,
                                             f16* __restrict__ out) {
  long i = ((long)blockIdx.x * 256 + threadIdx.x) * 4;
  f32x4 v = *(const f32x4*)(in + i);
  f16x4 o;
#pragma unroll
  for (int j = 0; j < 4; j++) o[j] = (f16)v[j];
  *(f16x4*)(out + i) = o;
}

// ---------------------------------------------------------------------------
// Transpose + cast: float in[R][C] -> f16 out[C][R].  block (32,8)
// ---------------------------------------------------------------------------
__global__ __launch_bounds__(256) void tcast(const float* __restrict__ in,
                                             f16* __restrict__ out, int R, int C) {
  __shared__ float tile[32][33];
  int tx = threadIdx.x, ty = threadIdx.y;
  int c = blockIdx.x * 32 + tx;
#pragma unroll
  for (int i = 0; i < 4; i++) {
    int r = blockIdx.y * 32 + ty + i * 8;
    tile[ty + i * 8][tx] = in[(long)r * C + c];
  }
  __syncthreads();
  int c2 = blockIdx.y * 32 + tx;
#pragma unroll
  for (int i = 0; i < 4; i++) {
    int r2 = blockIdx.x * 32 + ty + i * 8;
    out[(long)r2 * R + c2] = (f16)tile[tx][ty + i * 8];
  }
}

// ---------------------------------------------------------------------------
// V transpose: f16 src (qkv_f + 2048, row stride 3072) -> bf16 vtf in
// MFMA-fragment order (verified v6): element (bh, d, n) at
//   (((bh*32 + n>>6)*8 + (d>>5)*4 + ((n&63)>>4))*64 + ((n>>3)&1)*32 + (d&31))*8 + (n&7)
// ---------------------------------------------------------------------------
__global__ __launch_bounds__(256) void vtrans(const f16* __restrict__ src,
                                              bf16* __restrict__ vtf) {
  __shared__ f16 tile[32][33];
  int tx = threadIdx.x, ty = threadIdx.y;
  int n0 = blockIdx.x * 32, d0 = blockIdx.y * 32, bh = blockIdx.z;
  int b = bh >> 4, h = bh & 15;
#pragma unroll
  for (int i = 0; i < 4; i++) {
    int n = n0 + ty + i * 8;
    tile[ty + i * 8][tx] = src[(long)(b * 2048 + n) * 3072 + h * 64 + d0 + tx];
  }
  __syncthreads();
#pragma unroll
  for (int i = 0; i < 4; i++) {
    int d = d0 + ty + i * 8;
    int n = n0 + tx;
    long off = ((((long)bh * 32 + (n >> 6)) * 8 + (d >> 5) * 4 + ((n & 63) >> 4)) * 64 +
                ((n >> 3) & 1) * 32 + (d & 31)) * 8 + (n & 7);
    vtf[off] = (bf16)(float)tile[tx][ty + i * 8];
  }
}

// ---------------------------------------------------------------------------
// fp16 1-term GEMM: C[M,N] = A[M,K] @ B[N,K]^T. 128x128 tile, BK=32,
// fragment-order async staging, double-buffered (1 barrier/iter).
// ---------------------------------------------------------------------------
template <int MODE>
__global__ __launch_bounds__(512) void gemm_f16(const f16* __restrict__ A_g,
                                                const f16* __restrict__ B_g,
                                                float* __restrict__ p0,
                                                float* __restrict__ p1,
                                                f16* __restrict__ outh,
                                                int M, int N, int K) {
  __shared__ __align__(16) f16 AL[2][4096], BL[2][4096];
  int t = threadIdx.x, lane = t & 63, w = t >> 6;
  int wm = w >> 1, wn = w & 1;
  int m0 = blockIdx.y * 128, n0 = blockIdx.x * 128;
  int fm = lane & 15, fq = lane >> 4;
  int kseg = K / gridDim.z;
  int kstart = blockIdx.z * kseg;
  int nk = kseg / 32;

  const f16* ap = A_g + (long)(m0 + w * 16 + fm) * K + kstart + fq * 8;
  const f16* bp = B_g + (long)(n0 + w * 16 + fm) * K + kstart + fq * 8;

  f32x4 acc[2][4];
#pragma unroll
  for (int i = 0; i < 2; i++)
#pragma unroll
    for (int j = 0; j < 4; j++) acc[i][j] = f32x4{0.f, 0.f, 0.f, 0.f};

  async16(ap, &AL[0][w * 512]);
  async16(bp, &BL[0][w * 512]);

  for (int it = 0; it < nk; it++) {
    int cur = it & 1;
    __syncthreads();
    if (it < nk - 1) {
      int ko = (it + 1) * 32;
      async16(ap + ko, &AL[cur ^ 1][w * 512]);
      async16(bp + ko, &BL[cur ^ 1][w * 512]);
    }
    f16x8 a[2], bfr[4];
#pragma unroll
    for (int i = 0; i < 2; i++)
      a[i] = *(const f16x8*)&AL[cur][(wm * 2 + i) * 512 + lane * 8];
#pragma unroll
    for (int j = 0; j < 4; j++)
      bfr[j] = *(const f16x8*)&BL[cur][(wn * 4 + j) * 512 + lane * 8];
#pragma unroll
    for (int i = 0; i < 2; i++)
#pragma unroll
      for (int j = 0; j < 4; j++)
        acc[i][j] = __builtin_amdgcn_mfma_f32_16x16x32_f16(a[i], bfr[j], acc[i][j], 0, 0, 0);
  }

  float* dst = blockIdx.z ? p1 : p0;
#pragma unroll
  for (int i = 0; i < 2; i++)
#pragma unroll
    for (int j = 0; j < 4; j++) {
      int c = n0 + (wn * 4 + j) * 16 + fm;
#pragma unroll
      for (int e = 0; e < 4; e++) {
        int r = m0 + (wm * 2 + i) * 16 + fq * 4 + e;
        if (MODE == 0)
          dst[(long)r * N + c] = acc[i][j][e];
        else
          outh[(long)r * N + c] = (f16)acc[i][j][e];
      }
    }
}

// ---------------------------------------------------------------------------
// out = p0 + p1 + bias   (fp32, 4096x1024)
// ---------------------------------------------------------------------------
__global__ __launch_bounds__(256) void addbias(const float* __restrict__ p0,
                                               const float* __restrict__ p1,
                                               const float* __restrict__ bias,
                                               float* __restrict__ out) {
  long i = ((long)blockIdx.x * 256 + threadIdx.x) * 4;
  f32x4 a = *(const f32x4*)(p0 + i);
  f32x4 b = *(const f32x4*)(p1 + i);
  f32x4 c = *(const f32x4*)(bias + (i & 1023));
  *(f32x4*)(out + i) = a + b + c;
}

// ---------------------------------------------------------------------------
// RMSNorm (inner=1024) + RoPE, fp16 in (qkv_f, stride 3072), fp16 out.
// y==0 -> q row-major, scale 0.125*log2(e) (attn uses raw v_exp_f32 = 2^x);
// y==1 -> k in MFMA-fragment order (verified v6).
// ---------------------------------------------------------------------------
__global__ __launch_bounds__(256) void normrope(const f16* __restrict__ src,
                                                const float* __restrict__ wqn,
                                                const float* __restrict__ wkn,
                                                f16* __restrict__ qf,
                                                f16* __restrict__ kff) {
  int row = blockIdx.x, which = blockIdx.y;
  const f16* sp = src + (long)row * 3072 + which * 1024;
  const float* w = which ? wkn : wqn;
  float scale = which ? 1.0f : 0.18033688011112042f;  // 0.125 * log2(e)
  int t = threadIdx.x;
  int j0 = t * 4;

  f16x4 xh = *(const f16x4*)(sp + j0);
  float xv[4];
#pragma unroll
  for (int j = 0; j < 4; j++) xv[j] = (float)xh[j];
  float ss = xv[0] * xv[0] + xv[1] * xv[1] + xv[2] * xv[2] + xv[3] * xv[3];
#pragma unroll
  for (int off = 32; off > 0; off >>= 1) ss += __shfl_down(ss, off);
  __shared__ float red[4];
  if ((t & 63) == 0) red[t >> 6] = ss;
  __syncthreads();
  float total = red[0] + red[1] + red[2] + red[3];
  float nsc = rsqrtf(total * (1.0f / 1024.0f) + 1e-6f) * scale;

  int n = row & 2047;
  f16x4 o;
#pragma unroll
  for (int pp = 0; pp < 2; pp++) {
    int j = j0 + 2 * pp;
    int ii = (j & 63) >> 1;
    float theta = __expf((float)ii * (-9.210340371976184f / 32.0f));
    float ang = (float)n * theta;
    float sn, cs;
    __sincosf(ang, &sn, &cs);
    float a0 = xv[2 * pp] * nsc * w[j];
    float a1 = xv[2 * pp + 1] * nsc * w[j + 1];
    o[2 * pp] = (f16)(cs * a0 - sn * a1);
    o[2 * pp + 1] = (f16)(sn * a0 + cs * a1);
  }
  if (which == 0) {
    *(f16x4*)(qf + (long)row * 1024 + j0) = o;
  } else {
    int b2 = row >> 11;
    int h2 = j0 >> 6, dl = j0 & 63;
    long off = ((((long)(b2 * 16 + h2) * 32 + (n >> 6)) * 8 + ((n >> 5) & 1) * 4 +
                 (dl >> 4)) * 64 + ((dl >> 3) & 1) * 32 + (n & 31)) * 8 + (dl & 7);
    *(f16x4*)(kff + off) = o;
  }
}

// ---------------------------------------------------------------------------
// per-tile compute (v6-verified math): sequential-nt S^T = mfma(K,Q) with
// hoisted zero C-in, exp2 softmax (q pre-scaled by log2e), in-register P
// pack (cvt_pk + permlane32_swap), PV O^T += mfma(V^T, P^T).
// ---------------------------------------------------------------------------
__device__ __forceinline__ void attn_tile(const char* kbase, const char* vbase,
                                          const f16x8* qfr, const f32x16& Z,
                                          f32x16* Ot, float& l_, int la) {
  union PF {
    unsigned u[4];
    bf16x8 v;
  } pf[4];
#pragma unroll
  for (int nt = 0; nt < 2; nt++) {
    f16x8 k0 = *(const f16x8*)(kbase + (nt * 4 + 0) * 1024 + la);
    f16x8 k1 = *(const f16x8*)(kbase + (nt * 4 + 1) * 1024 + la);
    f16x8 k2 = *(const f16x8*)(kbase + (nt * 4 + 2) * 1024 + la);
    f16x8 k3 = *(const f16x8*)(kbase + (nt * 4 + 3) * 1024 + la);
    __builtin_amdgcn_s_setprio(1);
    f32x16 s = __builtin_amdgcn_mfma_f32_32x32x16_f16(k0, qfr[0], Z, 0, 0, 0);
    s = __builtin_amdgcn_mfma_f32_32x32x16_f16(k1, qfr[1], s, 0, 0, 0);
    s = __builtin_amdgcn_mfma_f32_32x32x16_f16(k2, qfr[2], s, 0, 0, 0);
    s = __builtin_amdgcn_mfma_f32_32x32x16_f16(k3, qfr[3], s, 0, 0, 0);
    __builtin_amdgcn_s_setprio(0);
    float pv[16];
#pragma unroll
    for (int r = 0; r < 16; r++) {
      pv[r] = exp2i(s[r]);
      l_ += pv[r];
    }
#pragma unroll
    for (int g = 0; g < 2; g++) {
      unsigned c01 = cvtpk(pv[g * 8 + 0], pv[g * 8 + 1]);
      unsigned c23 = cvtpk(pv[g * 8 + 2], pv[g * 8 + 3]);
      unsigned c45 = cvtpk(pv[g * 8 + 4], pv[g * 8 + 5]);
      unsigned c67 = cvtpk(pv[g * 8 + 6], pv[g * 8 + 7]);
      swap32(c01, c45);
      swap32(c23, c67);
      pf[nt * 2 + g].u[0] = c01;
      pf[nt * 2 + g].u[1] = c23;
      pf[nt * 2 + g].u[2] = c45;
      pf[nt * 2 + g].u[3] = c67;
    }
  }
  __builtin_amdgcn_s_setprio(1);
#pragma unroll
  for (int ks = 0; ks < 4; ks++) {
    bf16x8 v0 = *(const bf16x8*)(vbase + ks * 1024 + la);
    bf16x8 v1 = *(const bf16x8*)(vbase + (4 + ks) * 1024 + la);
    Ot[0] = __builtin_amdgcn_mfma_f32_32x32x16_bf16(v0, pf[ks].v, Ot[0], 0, 0, 0);
    Ot[1] = __builtin_amdgcn_mfma_f32_32x32x16_bf16(v1, pf[ks].v, Ot[1], 0, 0, 0);
  }
  __builtin_amdgcn_s_setprio(0);
}

// ---------------------------------------------------------------------------
// MFMA flash attention v7 = v6's verified dataflow (fragment-linear LDS,
// contiguous async16 staging, k-split z=b*2+ksp, pO/pl + combine) with a
// DEPTH-2 COUNTED-VMCNT PIPELINE (T3/T4): 3 LDS buffers; per iteration
//   s_waitcnt vmcnt(4)   (own 4 oldest DMAs done; next tile's 4 in flight)
//   s_barrier            (publishes tile `it` across waves)
//   STAGE(it+2)          (overwrites the buffer computed at it-1)
//   compute(it)
// No vmcnt(0) drain in the main loop. Memory-clobber asm fences pin the
// compiler-generated ds_reads between barriers.
// ---------------------------------------------------------------------------
__global__ __launch_bounds__(256) void attn_mfma(const f16* __restrict__ qf,
                                                 const f16* __restrict__ kff,
                                                 const bf16* __restrict__ vtf,
                                                 f16* __restrict__ pO,
                                                 float* __restrict__ pl) {
  // [0,24K): 3 K bufs x 8KB; [24K,48K): 3 V bufs x 8KB
  __shared__ __align__(16) char smem[49152];

  int t = threadIdx.x;
  int lane = t & 63, w = t >> 6;  // wave w owns q-rows q0 + w*32 .. +32
  int lo5 = lane & 31, hi = lane >> 5;
  int z = blockIdx.z;
  int b = z >> 1, ksp = z & 1;
  int h = blockIdx.y, q0 = blockIdx.x * 128;
  int la = lane * 16;

  // Q B-frags: lane -> Q[q0+w*32+lo5][h*64 + ks*16 + hi*8 + j]
  const f16* qb = qf + ((long)(b * 2048 + q0 + w * 32 + lo5)) * 1024 + h * 64 + hi * 8;
  f16x8 qfr[4];
#pragma unroll
  for (int ks = 0; ks < 4; ks++) qfr[ks] = *(const f16x8*)(qb + ks * 16);

  // contiguous fragment staging (verified v6): wave w stages units 2w, 2w+1
  const f16* kg = kff + ((long)(b * 16 + h)) * 131072 + (2 * w) * 512 + lane * 8;
  const bf16* vg = vtf + ((long)(b * 16 + h)) * 131072 + (2 * w) * 512 + lane * 8;

  f32x16 Ot[2];
#pragma unroll
  for (int i = 0; i < 16; i++) {
    Ot[0][i] = 0.f;
    Ot[1][i] = 0.f;
  }
  f32x16 Z;
#pragma unroll
  for (int i = 0; i < 16; i++) Z[i] = 0.f;
  float l_ = 0.f;

  int kb0 = ksp * 16;  // this block's half of the 32 k-tiles

#define STAGE(buf, kb)                                                        \
  {                                                                           \
    async16(kg + (long)(kb) * 4096, smem + (buf) * 8192 + (2 * w) * 1024);    \
    async16(kg + (long)(kb) * 4096 + 512,                                     \
            smem + (buf) * 8192 + (2 * w + 1) * 1024);                        \
    async16(vg + (long)(kb) * 4096,                                           \
            smem + 24576 + (buf) * 8192 + (2 * w) * 1024);                    \
    async16(vg + (long)(kb) * 4096 + 512,                                     \
            smem + 24576 + (buf) * 8192 + (2 * w + 1) * 1024);                \
  }

  STAGE(0, kb0);
  STAGE(1, kb0 + 1);

  int cur = 0;
  for (int it = 0; it < 15; it++) {
    asm volatile("s_waitcnt vmcnt(4)" ::: "memory");
    __builtin_amdgcn_s_barrier();
    asm volatile("" ::: "memory");
    if (it < 14) {
      int nb = cur + 2;
      if (nb >= 3) nb -= 3;
      STAGE(nb, kb0 + it + 2);
    }
    attn_tile(smem + cur * 8192, smem + 24576 + cur * 8192, qfr, Z, Ot, l_, la);
    cur++;
    if (cur == 3) cur = 0;
  }
  asm volatile("s_waitcnt vmcnt(0)" ::: "memory");
  __builtin_amdgcn_s_barrier();
  asm volatile("" ::: "memory");
  attn_tile(smem + cur * 8192, smem + 24576 + cur * 8192, qfr, Z, Ot, l_, la);
#undef STAGE

  // lane + its hi-partner hold complementary k halves for q=lo5
  l_ += __shfl_xor(l_, 32);
  float inv = 1.0f / l_;

  // per-split store (verified v5/v6): pO[ksp][b][h][q][d]
  long rowi = ((long)((ksp * 2 + b) * 16 + h)) * 2048 + q0 + w * 32 + lo5;
  f16* op = pO + rowi * 64;
#pragma unroll
  for (int dt = 0; dt < 2; dt++)
#pragma unroll
    for (int g4 = 0; g4 < 4; g4++) {
      f16x4 o4;
#pragma unroll
      for (int e = 0; e < 4; e++) o4[e] = (f16)(Ot[dt][g4 * 4 + e] * inv);
      *(f16x4*)(op + dt * 32 + g4 * 8 + hi * 4) = o4;
    }
  if (hi == 0) pl[rowi] = l_;
}

// ---------------------------------------------------------------------------
// combine the two k-split halves (verified v5/v6).
// ---------------------------------------------------------------------------
__global__ __launch_bounds__(256) void attn_combine(const f16* __restrict__ pO,
                                                    const float* __restrict__ pl,
                                                    f16* __restrict__ af) {
  int dg = threadIdx.x & 15;
  int qi = threadIdx.x >> 4;
  int q = blockIdx.x * 16 + qi;
  int h = blockIdx.y, b = blockIdx.z;
  long r0 = ((long)(b * 16 + h)) * 2048 + q;
  long r1 = ((long)((2 + b) * 16 + h)) * 2048 + q;
  float l0 = pl[r0], l1 = pl[r1];
  float w0 = l0 / (l0 + l1), w1 = 1.0f - w0;
  f16x4 a = *(const f16x4*)(pO + r0 * 64 + dg * 4);
  f16x4 c = *(const f16x4*)(pO + r1 * 64 + dg * 4);
  f16x4 o;
#pragma unroll
  for (int e = 0; e < 4; e++) o[e] = (f16)((float)a[e] * w0 + (float)c[e] * w1);
  *(f16x4*)(af + ((long)(b * 2048 + q)) * 1024 + h * 64 + dg * 4) = o;
}

// ---------------------------------------------------------------------------
// Workspace (MB, peak 62; 76 proven safe), liveness:
//   [ 0, 8): xf        castx -> qkv-GEMM
//   [ 8,14): Wqkv_t    tcast x2 -> qkv-GEMM
//   [14,38): qkv_f     GEMM -> normrope / vtrans
//   [38,46): qf        normrope -> attn
//   [46,54): kff       normrope (fragment order) -> attn
//   [54,62): vtf       vtrans (fragment order) -> attn
//   [14,30): pO        attn partials -> combine   (qkv_f dead)
//   [30,31): pl        attn denominators -> combine
//   [ 0, 8): af        combine -> out-GEMM        (xf dead)
//   [ 8,10): Wo_t      tcast -> out-GEMM          (Wqkv_t dead)
//   [14,30): p0        out-GEMM -> addbias        (pO dead)
//   [30,46): p1        out-GEMM -> addbias        (pl + qf dead)
// ---------------------------------------------------------------------------
extern "C" void kernel_launch(void* const* d_in, const int* in_sizes, int n_in,
                              void* d_out, int out_size, void* d_ws, size_t ws_size,
                              hipStream_t stream) {
  const float* x = (const float*)d_in[0];
  const float* Wq = (const float*)d_in[1];
  const float* Wkv = (const float*)d_in[2];
  const float* nqw = (const float*)d_in[3];
  const float* nkw = (const float*)d_in[4];
  const float* Wo = (const float*)d_in[5];
  const float* bo = (const float*)d_in[6];
  float* out = (float*)d_out;

  char* ws = (char*)d_ws;
  const long MB = 1l << 20;
  f16* xf     = (f16*)(ws);
  f16* Wqkv_t = (f16*)(ws + 8 * MB);
  f16* qkv_f  = (f16*)(ws + 14 * MB);
  f16* qfb    = (f16*)(ws + 38 * MB);
  f16* kffb   = (f16*)(ws + 46 * MB);
  bf16* vtfb  = (bf16*)(ws + 54 * MB);
  f16* pOb    = (f16*)(ws + 14 * MB);
  float* plb  = (float*)(ws + 30 * MB);
  f16* afb    = (f16*)(ws);
  f16* Wo_t   = (f16*)(ws + 8 * MB);
  float* p0   = (float*)(ws + 14 * MB);
  float* p1   = (float*)(ws + 30 * MB);

  dim3 tb(32, 8);
  castx<<<4096, 256, 0, stream>>>(x, xf);
  tcast<<<dim3(32, 32), tb, 0, stream>>>(Wq, Wqkv_t, 1024, 1024);
  tcast<<<dim3(64, 32), tb, 0, stream>>>(Wkv, Wqkv_t + 1024l * 1024, 1024, 2048);

  gemm_f16<1><<<dim3(24, 32), 512, 0, stream>>>(xf, Wqkv_t, nullptr, nullptr,
                                                qkv_f, 4096, 3072, 1024);

  normrope<<<dim3(4096, 2), 256, 0, stream>>>(qkv_f, nqw, nkw, qfb, kffb);

  vtrans<<<dim3(64, 2, 32), tb, 0, stream>>>(qkv_f + 2048, vtfb);

  attn_mfma<<<dim3(16, 16, 4), 256, 0, stream>>>(qfb, kffb, vtfb, pOb, plb);

  attn_combine<<<dim3(128, 16, 2), 256, 0, stream>>>(pOb, plb, afb);

  tcast<<<dim3(32, 32), tb, 0, stream>>>(Wo, Wo_t, 1024, 1024);

  gemm_f16<0><<<dim3(8, 32, 2), 512, 0, stream>>>(afb, Wo_t, p0, p1, nullptr,
                                                  4096, 1024, 1024);

  addbias<<<4096, 256, 0, stream>>>(p0, p1, bo, out);
}

// Round 7
// 247.120 us; speedup vs baseline: 1.0213x; 1.0200x over previous
//
#include <hip/hip_runtime.h>

typedef __bf16 bf16;
typedef _Float16 f16;
typedef __bf16 bf16x8 __attribute__((ext_vector_type(8)));
typedef _Float16 f16x4 __attribute__((ext_vector_type(4)));
typedef _Float16 f16x8 __attribute__((ext_vector_type(8)));
typedef float f32x4 __attribute__((ext_vector_type(4)));
typedef float f32x16 __attribute__((ext_vector_type(16)));

// async global->LDS, 16B/lane. LDS dest = wave-uniform base + lane*16.
__device__ __forceinline__ void async16(const void* g, void* l) {
  __builtin_amdgcn_global_load_lds(
      (const __attribute__((address_space(1))) unsigned int*)g,
      (__attribute__((address_space(3))) unsigned int*)l, 16, 0, 0);
}

// pack two f32 -> one dword of 2x bf16 (no builtin on gfx950)
__device__ __forceinline__ unsigned cvtpk(float a, float b) {
  unsigned r;
  asm("v_cvt_pk_bf16_f32 %0, %1, %2" : "=v"(r) : "v"(a), "v"(b));
  return r;
}

// exchange a[32..63] <-> b[0..31]
__device__ __forceinline__ void swap32(unsigned& a, unsigned& b) {
  asm("v_permlane32_swap_b32 %0, %1" : "+v"(a), "+v"(b));
}

// raw v_exp_f32: 2^x (q is pre-scaled by log2e upstream)
__device__ __forceinline__ float exp2i(float x) {
  float r;
  asm("v_exp_f32 %0, %1" : "=v"(r) : "v"(x));
  return r;
}

// ---------------------------------------------------------------------------
// Cast fp32 -> fp16, vectorized x4
// ---------------------------------------------------------------------------
__global__ __launch_bounds__(256) void castx(const float* __restrict__ in,
                                             f16* __restrict__ out) {
  long i = ((long)blockIdx.x * 256 + threadIdx.x) * 4;
  f32x4 v = *(const f32x4*)(in + i);
  f16x4 o;
#pragma unroll
  for (int j = 0; j < 4; j++) o[j] = (f16)v[j];
  *(f16x4*)(out + i) = o;
}

// ---------------------------------------------------------------------------
// Transpose + cast: float in[R][C] -> f16 out[C][R].  block (32,8)
// ---------------------------------------------------------------------------
__global__ __launch_bounds__(256) void tcast(const float* __restrict__ in,
                                             f16* __restrict__ out, int R, int C) {
  __shared__ float tile[32][33];
  int tx = threadIdx.x, ty = threadIdx.y;
  int c = blockIdx.x * 32 + tx;
#pragma unroll
  for (int i = 0; i < 4; i++) {
    int r = blockIdx.y * 32 + ty + i * 8;
    tile[ty + i * 8][tx] = in[(long)r * C + c];
  }
  __syncthreads();
  int c2 = blockIdx.y * 32 + tx;
#pragma unroll
  for (int i = 0; i < 4; i++) {
    int r2 = blockIdx.x * 32 + ty + i * 8;
    out[(long)r2 * R + c2] = (f16)tile[tx][ty + i * 8];
  }
}

// ---------------------------------------------------------------------------
// V transpose: f16 src (qkv_f + 2048, row stride 3072) -> bf16 vtf in
// MFMA-fragment order (verified v6): element (bh, d, n) at
//   (((bh*32 + n>>6)*8 + (d>>5)*4 + ((n&63)>>4))*64 + ((n>>3)&1)*32 + (d&31))*8 + (n&7)
// ---------------------------------------------------------------------------
__global__ __launch_bounds__(256) void vtrans(const f16* __restrict__ src,
                                              bf16* __restrict__ vtf) {
  __shared__ f16 tile[32][33];
  int tx = threadIdx.x, ty = threadIdx.y;
  int n0 = blockIdx.x * 32, d0 = blockIdx.y * 32, bh = blockIdx.z;
  int b = bh >> 4, h = bh & 15;
#pragma unroll
  for (int i = 0; i < 4; i++) {
    int n = n0 + ty + i * 8;
    tile[ty + i * 8][tx] = src[(long)(b * 2048 + n) * 3072 + h * 64 + d0 + tx];
  }
  __syncthreads();
#pragma unroll
  for (int i = 0; i < 4; i++) {
    int d = d0 + ty + i * 8;
    int n = n0 + tx;
    long off = ((((long)bh * 32 + (n >> 6)) * 8 + (d >> 5) * 4 + ((n & 63) >> 4)) * 64 +
                ((n >> 3) & 1) * 32 + (d & 31)) * 8 + (n & 7);
    vtf[off] = (bf16)(float)tile[tx][ty + i * 8];
  }
}

// ---------------------------------------------------------------------------
// fp16 1-term GEMM: C[M,N] = A[M,K] @ B[N,K]^T. 128x128 tile, BK=32,
// fragment-order async staging. v8: DEPTH-2 COUNTED-VMCNT PIPELINE (the
// HW-verified v7 attn structure): 3 LDS buffers; per iteration
//   s_waitcnt vmcnt(2)  (own 2 DMAs of tile `it` done; tile it+1's in flight)
//   s_barrier -> STAGE(it+2) -> compute(it).  No vmcnt(0) in the main loop.
// 512 threads / 8 waves: wave = (wm 0..3, wn 0..1), 32x64 output each.
// MODE 0: fp32 partials via blockIdx.z split-K. MODE 1: f16 out.
// ---------------------------------------------------------------------------
template <int MODE>
__global__ __launch_bounds__(512) void gemm_f16(const f16* __restrict__ A_g,
                                                const f16* __restrict__ B_g,
                                                float* __restrict__ p0,
                                                float* __restrict__ p1,
                                                f16* __restrict__ outh,
                                                int M, int N, int K) {
  __shared__ __align__(16) f16 AL[3][4096], BL[3][4096];
  int t = threadIdx.x, lane = t & 63, w = t >> 6;
  int wm = w >> 1, wn = w & 1;
  int m0 = blockIdx.y * 128, n0 = blockIdx.x * 128;
  int fm = lane & 15, fq = lane >> 4;
  int kseg = K / gridDim.z;
  int kstart = blockIdx.z * kseg;
  int nk = kseg / 32;

  const f16* ap = A_g + (long)(m0 + w * 16 + fm) * K + kstart + fq * 8;
  const f16* bp = B_g + (long)(n0 + w * 16 + fm) * K + kstart + fq * 8;

  f32x4 acc[2][4];
#pragma unroll
  for (int i = 0; i < 2; i++)
#pragma unroll
    for (int j = 0; j < 4; j++) acc[i][j] = f32x4{0.f, 0.f, 0.f, 0.f};

#define GSTAGE(buf, tt)                        \
  {                                            \
    async16(ap + (tt) * 32, &AL[buf][w * 512]); \
    async16(bp + (tt) * 32, &BL[buf][w * 512]); \
  }
#define GCOMP(buf)                                                             \
  {                                                                            \
    f16x8 a[2], bfr[4];                                                        \
    _Pragma("unroll") for (int i = 0; i < 2; i++)                              \
        a[i] = *(const f16x8*)&AL[buf][(wm * 2 + i) * 512 + lane * 8];         \
    _Pragma("unroll") for (int j = 0; j < 4; j++)                              \
        bfr[j] = *(const f16x8*)&BL[buf][(wn * 4 + j) * 512 + lane * 8];       \
    _Pragma("unroll") for (int i = 0; i < 2; i++)                              \
        _Pragma("unroll") for (int j = 0; j < 4; j++)                          \
            acc[i][j] = __builtin_amdgcn_mfma_f32_16x16x32_f16(a[i], bfr[j],   \
                                                               acc[i][j], 0,  \
                                                               0, 0);          \
  }

  GSTAGE(0, 0);
  GSTAGE(1, 1);

  int cur = 0;
  for (int it = 0; it < nk - 1; it++) {
    asm volatile("s_waitcnt vmcnt(2)" ::: "memory");
    __builtin_amdgcn_s_barrier();
    asm volatile("" ::: "memory");
    if (it < nk - 2) {
      int nb = cur + 2;
      if (nb >= 3) nb -= 3;
      GSTAGE(nb, it + 2);
    }
    GCOMP(cur);
    cur++;
    if (cur == 3) cur = 0;
  }
  asm volatile("s_waitcnt vmcnt(0)" ::: "memory");
  __builtin_amdgcn_s_barrier();
  asm volatile("" ::: "memory");
  GCOMP(cur);
#undef GSTAGE
#undef GCOMP

  float* dst = blockIdx.z ? p1 : p0;
#pragma unroll
  for (int i = 0; i < 2; i++)
#pragma unroll
    for (int j = 0; j < 4; j++) {
      int c = n0 + (wn * 4 + j) * 16 + fm;
#pragma unroll
      for (int e = 0; e < 4; e++) {
        int r = m0 + (wm * 2 + i) * 16 + fq * 4 + e;
        if (MODE == 0)
          dst[(long)r * N + c] = acc[i][j][e];
        else
          outh[(long)r * N + c] = (f16)acc[i][j][e];
      }
    }
}

// ---------------------------------------------------------------------------
// out = p0 + p1 + bias   (fp32, 4096x1024)
// ---------------------------------------------------------------------------
__global__ __launch_bounds__(256) void addbias(const float* __restrict__ p0,
                                               const float* __restrict__ p1,
                                               const float* __restrict__ bias,
                                               float* __restrict__ out) {
  long i = ((long)blockIdx.x * 256 + threadIdx.x) * 4;
  f32x4 a = *(const f32x4*)(p0 + i);
  f32x4 b = *(const f32x4*)(p1 + i);
  f32x4 c = *(const f32x4*)(bias + (i & 1023));
  *(f32x4*)(out + i) = a + b + c;
}

// ---------------------------------------------------------------------------
// RMSNorm (inner=1024) + RoPE, fp16 in (qkv_f, stride 3072), fp16 out.
// y==0 -> q row-major, scale 0.125*log2(e) (attn uses raw v_exp_f32 = 2^x);
// y==1 -> k in MFMA-fragment order (verified v6).
// ---------------------------------------------------------------------------
__global__ __launch_bounds__(256) void normrope(const f16* __restrict__ src,
                                                const float* __restrict__ wqn,
                                                const float* __restrict__ wkn,
                                                f16* __restrict__ qf,
                                                f16* __restrict__ kff) {
  int row = blockIdx.x, which = blockIdx.y;
  const f16* sp = src + (long)row * 3072 + which * 1024;
  const float* w = which ? wkn : wqn;
  float scale = which ? 1.0f : 0.18033688011112042f;  // 0.125 * log2(e)
  int t = threadIdx.x;
  int j0 = t * 4;

  f16x4 xh = *(const f16x4*)(sp + j0);
  float xv[4];
#pragma unroll
  for (int j = 0; j < 4; j++) xv[j] = (float)xh[j];
  float ss = xv[0] * xv[0] + xv[1] * xv[1] + xv[2] * xv[2] + xv[3] * xv[3];
#pragma unroll
  for (int off = 32; off > 0; off >>= 1) ss += __shfl_down(ss, off);
  __shared__ float red[4];
  if ((t & 63) == 0) red[t >> 6] = ss;
  __syncthreads();
  float total = red[0] + red[1] + red[2] + red[3];
  float nsc = rsqrtf(total * (1.0f / 1024.0f) + 1e-6f) * scale;

  int n = row & 2047;
  f16x4 o;
#pragma unroll
  for (int pp = 0; pp < 2; pp++) {
    int j = j0 + 2 * pp;
    int ii = (j & 63) >> 1;
    float theta = __expf((float)ii * (-9.210340371976184f / 32.0f));
    float ang = (float)n * theta;
    float sn, cs;
    __sincosf(ang, &sn, &cs);
    float a0 = xv[2 * pp] * nsc * w[j];
    float a1 = xv[2 * pp + 1] * nsc * w[j + 1];
    o[2 * pp] = (f16)(cs * a0 - sn * a1);
    o[2 * pp + 1] = (f16)(sn * a0 + cs * a1);
  }
  if (which == 0) {
    *(f16x4*)(qf + (long)row * 1024 + j0) = o;
  } else {
    int b2 = row >> 11;
    int h2 = j0 >> 6, dl = j0 & 63;
    long off = ((((long)(b2 * 16 + h2) * 32 + (n >> 6)) * 8 + ((n >> 5) & 1) * 4 +
                 (dl >> 4)) * 64 + ((dl >> 3) & 1) * 32 + (n & 31)) * 8 + (dl & 7);
    *(f16x4*)(kff + off) = o;
  }
}

// ---------------------------------------------------------------------------
// per-tile compute (v6-verified math): sequential-nt S^T = mfma(K,Q) with
// hoisted zero C-in, exp2 softmax (q pre-scaled by log2e), in-register P
// pack (cvt_pk + permlane32_swap), PV O^T += mfma(V^T, P^T).
// ---------------------------------------------------------------------------
__device__ __forceinline__ void attn_tile(const char* kbase, const char* vbase,
                                          const f16x8* qfr, const f32x16& Z,
                                          f32x16* Ot, float& l_, int la) {
  union PF {
    unsigned u[4];
    bf16x8 v;
  } pf[4];
#pragma unroll
  for (int nt = 0; nt < 2; nt++) {
    f16x8 k0 = *(const f16x8*)(kbase + (nt * 4 + 0) * 1024 + la);
    f16x8 k1 = *(const f16x8*)(kbase + (nt * 4 + 1) * 1024 + la);
    f16x8 k2 = *(const f16x8*)(kbase + (nt * 4 + 2) * 1024 + la);
    f16x8 k3 = *(const f16x8*)(kbase + (nt * 4 + 3) * 1024 + la);
    __builtin_amdgcn_s_setprio(1);
    f32x16 s = __builtin_amdgcn_mfma_f32_32x32x16_f16(k0, qfr[0], Z, 0, 0, 0);
    s = __builtin_amdgcn_mfma_f32_32x32x16_f16(k1, qfr[1], s, 0, 0, 0);
    s = __builtin_amdgcn_mfma_f32_32x32x16_f16(k2, qfr[2], s, 0, 0, 0);
    s = __builtin_amdgcn_mfma_f32_32x32x16_f16(k3, qfr[3], s, 0, 0, 0);
    __builtin_amdgcn_s_setprio(0);
    float pv[16];
#pragma unroll
    for (int r = 0; r < 16; r++) {
      pv[r] = exp2i(s[r]);
      l_ += pv[r];
    }
#pragma unroll
    for (int g = 0; g < 2; g++) {
      unsigned c01 = cvtpk(pv[g * 8 + 0], pv[g * 8 + 1]);
      unsigned c23 = cvtpk(pv[g * 8 + 2], pv[g * 8 + 3]);
      unsigned c45 = cvtpk(pv[g * 8 + 4], pv[g * 8 + 5]);
      unsigned c67 = cvtpk(pv[g * 8 + 6], pv[g * 8 + 7]);
      swap32(c01, c45);
      swap32(c23, c67);
      pf[nt * 2 + g].u[0] = c01;
      pf[nt * 2 + g].u[1] = c23;
      pf[nt * 2 + g].u[2] = c45;
      pf[nt * 2 + g].u[3] = c67;
    }
  }
  __builtin_amdgcn_s_setprio(1);
#pragma unroll
  for (int ks = 0; ks < 4; ks++) {
    bf16x8 v0 = *(const bf16x8*)(vbase + ks * 1024 + la);
    bf16x8 v1 = *(const bf16x8*)(vbase + (4 + ks) * 1024 + la);
    Ot[0] = __builtin_amdgcn_mfma_f32_32x32x16_bf16(v0, pf[ks].v, Ot[0], 0, 0, 0);
    Ot[1] = __builtin_amdgcn_mfma_f32_32x32x16_bf16(v1, pf[ks].v, Ot[1], 0, 0, 0);
  }
  __builtin_amdgcn_s_setprio(0);
}

// ---------------------------------------------------------------------------
// MFMA flash attention v7 (verified): fragment-linear LDS, contiguous async16
// staging, k-split z=b*2+ksp, depth-2 counted-vmcnt pipeline, pO/pl + combine.
// ---------------------------------------------------------------------------
__global__ __launch_bounds__(256) void attn_mfma(const f16* __restrict__ qf,
                                                 const f16* __restrict__ kff,
                                                 const bf16* __restrict__ vtf,
                                                 f16* __restrict__ pO,
                                                 float* __restrict__ pl) {
  // [0,24K): 3 K bufs x 8KB; [24K,48K): 3 V bufs x 8KB
  __shared__ __align__(16) char smem[49152];

  int t = threadIdx.x;
  int lane = t & 63, w = t >> 6;  // wave w owns q-rows q0 + w*32 .. +32
  int lo5 = lane & 31, hi = lane >> 5;
  int z = blockIdx.z;
  int b = z >> 1, ksp = z & 1;
  int h = blockIdx.y, q0 = blockIdx.x * 128;
  int la = lane * 16;

  // Q B-frags: lane -> Q[q0+w*32+lo5][h*64 + ks*16 + hi*8 + j]
  const f16* qb = qf + ((long)(b * 2048 + q0 + w * 32 + lo5)) * 1024 + h * 64 + hi * 8;
  f16x8 qfr[4];
#pragma unroll
  for (int ks = 0; ks < 4; ks++) qfr[ks] = *(const f16x8*)(qb + ks * 16);

  // contiguous fragment staging (verified v6): wave w stages units 2w, 2w+1
  const f16* kg = kff + ((long)(b * 16 + h)) * 131072 + (2 * w) * 512 + lane * 8;
  const bf16* vg = vtf + ((long)(b * 16 + h)) * 131072 + (2 * w) * 512 + lane * 8;

  f32x16 Ot[2];
#pragma unroll
  for (int i = 0; i < 16; i++) {
    Ot[0][i] = 0.f;
    Ot[1][i] = 0.f;
  }
  f32x16 Z;
#pragma unroll
  for (int i = 0; i < 16; i++) Z[i] = 0.f;
  float l_ = 0.f;

  int kb0 = ksp * 16;  // this block's half of the 32 k-tiles

#define STAGE(buf, kb)                                                        \
  {                                                                           \
    async16(kg + (long)(kb) * 4096, smem + (buf) * 8192 + (2 * w) * 1024);    \
    async16(kg + (long)(kb) * 4096 + 512,                                     \
            smem + (buf) * 8192 + (2 * w + 1) * 1024);                        \
    async16(vg + (long)(kb) * 4096,                                           \
            smem + 24576 + (buf) * 8192 + (2 * w) * 1024);                    \
    async16(vg + (long)(kb) * 4096 + 512,                                     \
            smem + 24576 + (buf) * 8192 + (2 * w + 1) * 1024);                \
  }

  STAGE(0, kb0);
  STAGE(1, kb0 + 1);

  int cur = 0;
  for (int it = 0; it < 15; it++) {
    asm volatile("s_waitcnt vmcnt(4)" ::: "memory");
    __builtin_amdgcn_s_barrier();
    asm volatile("" ::: "memory");
    if (it < 14) {
      int nb = cur + 2;
      if (nb >= 3) nb -= 3;
      STAGE(nb, kb0 + it + 2);
    }
    attn_tile(smem + cur * 8192, smem + 24576 + cur * 8192, qfr, Z, Ot, l_, la);
    cur++;
    if (cur == 3) cur = 0;
  }
  asm volatile("s_waitcnt vmcnt(0)" ::: "memory");
  __builtin_amdgcn_s_barrier();
  asm volatile("" ::: "memory");
  attn_tile(smem + cur * 8192, smem + 24576 + cur * 8192, qfr, Z, Ot, l_, la);
#undef STAGE

  // lane + its hi-partner hold complementary k halves for q=lo5
  l_ += __shfl_xor(l_, 32);
  float inv = 1.0f / l_;

  // per-split store (verified v5/v6): pO[ksp][b][h][q][d]
  long rowi = ((long)((ksp * 2 + b) * 16 + h)) * 2048 + q0 + w * 32 + lo5;
  f16* op = pO + rowi * 64;
#pragma unroll
  for (int dt = 0; dt < 2; dt++)
#pragma unroll
    for (int g4 = 0; g4 < 4; g4++) {
      f16x4 o4;
#pragma unroll
      for (int e = 0; e < 4; e++) o4[e] = (f16)(Ot[dt][g4 * 4 + e] * inv);
      *(f16x4*)(op + dt * 32 + g4 * 8 + hi * 4) = o4;
    }
  if (hi == 0) pl[rowi] = l_;
}

// ---------------------------------------------------------------------------
// combine the two k-split halves (verified v5/v6).
// ---------------------------------------------------------------------------
__global__ __launch_bounds__(256) void attn_combine(const f16* __restrict__ pO,
                                                    const float* __restrict__ pl,
                                                    f16* __restrict__ af) {
  int dg = threadIdx.x & 15;
  int qi = threadIdx.x >> 4;
  int q = blockIdx.x * 16 + qi;
  int h = blockIdx.y, b = blockIdx.z;
  long r0 = ((long)(b * 16 + h)) * 2048 + q;
  long r1 = ((long)((2 + b) * 16 + h)) * 2048 + q;
  float l0 = pl[r0], l1 = pl[r1];
  float w0 = l0 / (l0 + l1), w1 = 1.0f - w0;
  f16x4 a = *(const f16x4*)(pO + r0 * 64 + dg * 4);
  f16x4 c = *(const f16x4*)(pO + r1 * 64 + dg * 4);
  f16x4 o;
#pragma unroll
  for (int e = 0; e < 4; e++) o[e] = (f16)((float)a[e] * w0 + (float)c[e] * w1);
  *(f16x4*)(af + ((long)(b * 2048 + q)) * 1024 + h * 64 + dg * 4) = o;
}

// ---------------------------------------------------------------------------
// Workspace (MB, peak 62; 76 proven safe), liveness:
//   [ 0, 8): xf        castx -> qkv-GEMM
//   [ 8,14): Wqkv_t    tcast x2 -> qkv-GEMM
//   [14,38): qkv_f     GEMM -> normrope / vtrans
//   [38,46): qf        normrope -> attn
//   [46,54): kff       normrope (fragment order) -> attn
//   [54,62): vtf       vtrans (fragment order) -> attn
//   [14,30): pO        attn partials -> combine   (qkv_f dead)
//   [30,31): pl        attn denominators -> combine
//   [ 0, 8): af        combine -> out-GEMM        (xf dead)
//   [ 8,10): Wo_t      tcast -> out-GEMM          (Wqkv_t dead)
//   [14,30): p0        out-GEMM -> addbias        (pO dead)
//   [30,46): p1        out-GEMM -> addbias        (pl + qf dead)
// ---------------------------------------------------------------------------
extern "C" void kernel_launch(void* const* d_in, const int* in_sizes, int n_in,
                              void* d_out, int out_size, void* d_ws, size_t ws_size,
                              hipStream_t stream) {
  const float* x = (const float*)d_in[0];
  const float* Wq = (const float*)d_in[1];
  const float* Wkv = (const float*)d_in[2];
  const float* nqw = (const float*)d_in[3];
  const float* nkw = (const float*)d_in[4];
  const float* Wo = (const float*)d_in[5];
  const float* bo = (const float*)d_in[6];
  float* out = (float*)d_out;

  char* ws = (char*)d_ws;
  const long MB = 1l << 20;
  f16* xf     = (f16*)(ws);
  f16* Wqkv_t = (f16*)(ws + 8 * MB);
  f16* qkv_f  = (f16*)(ws + 14 * MB);
  f16* qfb    = (f16*)(ws + 38 * MB);
  f16* kffb   = (f16*)(ws + 46 * MB);
  bf16* vtfb  = (bf16*)(ws + 54 * MB);
  f16* pOb    = (f16*)(ws + 14 * MB);
  float* plb  = (float*)(ws + 30 * MB);
  f16* afb    = (f16*)(ws);
  f16* Wo_t   = (f16*)(ws + 8 * MB);
  float* p0   = (float*)(ws + 14 * MB);
  float* p1   = (float*)(ws + 30 * MB);

  dim3 tb(32, 8);
  castx<<<4096, 256, 0, stream>>>(x, xf);
  tcast<<<dim3(32, 32), tb, 0, stream>>>(Wq, Wqkv_t, 1024, 1024);
  tcast<<<dim3(64, 32), tb, 0, stream>>>(Wkv, Wqkv_t + 1024l * 1024, 1024, 2048);

  gemm_f16<1><<<dim3(24, 32), 512, 0, stream>>>(xf, Wqkv_t, nullptr, nullptr,
                                                qkv_f, 4096, 3072, 1024);

  normrope<<<dim3(4096, 2), 256, 0, stream>>>(qkv_f, nqw, nkw, qfb, kffb);

  vtrans<<<dim3(64, 2, 32), tb, 0, stream>>>(qkv_f + 2048, vtfb);

  attn_mfma<<<dim3(16, 16, 4), 256, 0, stream>>>(qfb, kffb, vtfb, pOb, plb);

  attn_combine<<<dim3(128, 16, 2), 256, 0, stream>>>(pOb, plb, afb);

  tcast<<<dim3(32, 32), tb, 0, stream>>>(Wo, Wo_t, 1024, 1024);

  gemm_f16<0><<<dim3(8, 32, 2), 512, 0, stream>>>(afb, Wo_t, p0, p1, nullptr,
                                                  4096, 1024, 1024);

  addbias<<<4096, 256, 0, stream>>>(p0, p1, bo, out);
}